// Round 4
// baseline (2148.634 us; speedup 1.0000x reference)
//
#include <hip/hip_runtime.h>

// bf16 MFMA fragment types per cdna_hip_programming.md §3
typedef short short8 __attribute__((ext_vector_type(8)));   // 8 bf16 (4 VGPRs)
typedef float f32x4 __attribute__((ext_vector_type(4)));    // 4 fp32 acc
typedef unsigned int uint4v __attribute__((ext_vector_type(4)));

static constexpr int kH = 128;   // hidden dim

// fp32 -> bf16 round-to-nearest-even, manual (no HIP class types: bit_cast-safe)
__device__ __forceinline__ unsigned f2bf(float f) {
    unsigned u = __builtin_bit_cast(unsigned, f);
    u += 0x7fffu + ((u >> 16) & 1u);
    return u >> 16;
}
__device__ __forceinline__ unsigned pack_bf16x2(float a, float b) {
    return f2bf(a) | (f2bf(b) << 16);   // a = element 0 (low 16)
}

struct U128 { unsigned x, y, z, w; };

// ---------- W1 -> LDS fill (MFMA B-fragment order), verified in rounds 2-3 ----------
// uint index lin2 = ((s*8+nt)*64 + lane)*4 + (j/2)
//   = B[n = nt*16+(lane&15)][k = s*32+(lane>>4)*8+j], lane-contiguous 16 B -> conflict-free ds_read_b128
template <int BLK>
__device__ __forceinline__ void fill_w1(const float* __restrict__ W1, unsigned* ldsB, int tid) {
    #pragma unroll 4
    for (int i = 0; i < 16384 / BLK; ++i) {
        int lin2 = tid + i * BLK;
        int j  = (lin2 & 3) * 2;
        int l  = (lin2 >> 2) & 63;
        int nt = (lin2 >> 8) & 7;
        int s  = (lin2 >> 11) & 7;
        int q = l >> 4, n = l & 15;
        int k = s * 32 + q * 8 + j;
        int ncol = nt * 16 + n;
        ldsB[lin2] = pack_bf16x2(W1[k * kH + ncol], W1[(k + 1) * kH + ncol]);
    }
}

// Block = 512 thr (8 waves), 64 KiB LDS -> 2 blocks/CU = 16 waves/CU; VGPR must stay <=128.
// Each wave: 16 edges/tile (1 M-tile). Depth-4 rotating register pipeline over the 8 k-slices
// keeps ~8 KB of gather loads in flight per wave (vs ~4 KB briefly in rounds 2-3).
__global__ __launch_bounds__(512, 4) void edge_mlp_f32(
    const float* __restrict__ zc, const float* __restrict__ za,
    const int* __restrict__ row, const int* __restrict__ col,
    const float* __restrict__ W1, const float* __restrict__ b1,
    const float* __restrict__ W2, const float* __restrict__ b2,
    float* __restrict__ out, int E, int ntiles)
{
    __shared__ unsigned ldsB[16384];  // 64 KiB
    const int tid = threadIdx.x;
    fill_w1<512>(W1, ldsB, tid);
    __syncthreads();   // only barrier; waves run free afterwards

    const int w   = tid >> 6;   // wave 0..7
    const int l   = tid & 63;
    const int q   = l >> 4;     // k-chunk within slice / C-row group
    const int n16 = l & 15;     // edge within M-tile / C-col

    float b1v[8], w2v[8];
    #pragma unroll
    for (int nt = 0; nt < 8; ++nt) {
        b1v[nt] = b1[nt * 16 + n16];
        w2v[nt] = W2[nt * 16 + n16];
    }
    const float b2s = b2[0];
    const int stride = gridDim.x;

    int tile = blockIdx.x;
    if (tile >= ntiles) return;

    // indices for the first tile (each subsequent tile's indices prefetched a tile ahead)
    int ce = min(tile * 128 + w * 16 + n16, E - 1);
    int r0 = row[ce], c0 = col[ce];

    for (; tile < ntiles; tile += stride) {
        const float* pc = zc + (size_t)r0 * kH;   // this edge's customer row (512 B)
        const float* pa = za + (size_t)c0 * kH;   // this edge's article row (512 B)

        // prefetch next tile's indices now (full tile of latency to hide)
        int ntile = tile + stride;
        int nce = min(min(ntile, ntiles - 1) * 128 + w * 16 + n16, E - 1);
        int nr = row[nce], nc = col[nce];

        float4 P[4][2];   // 4-deep slice pipeline, 32 B/slice/lane
        auto ld = [&](int d, int s) {
            const float* sp = (s < 4) ? (pc + s * 32) : (pa + (s - 4) * 32);
            P[d][0] = *(const float4*)(sp + q * 8);
            P[d][1] = *(const float4*)(sp + q * 8 + 4);
        };
        ld(0, 0); ld(1, 1); ld(2, 2); ld(3, 3);

        f32x4 acc[8];
        #pragma unroll
        for (int nt = 0; nt < 8; ++nt) acc[nt] = f32x4{0.f, 0.f, 0.f, 0.f};

        #pragma unroll
        for (int s = 0; s < 8; ++s) {
            const int d = s & 3;
            float4 fa = P[d][0], fb = P[d][1];
            U128 ua{pack_bf16x2(fa.x, fa.y), pack_bf16x2(fa.z, fa.w),
                    pack_bf16x2(fb.x, fb.y), pack_bf16x2(fb.z, fb.w)};
            short8 a0 = __builtin_bit_cast(short8, ua);
            if (s < 4) ld(d, s + 4);   // refill the slot just consumed
            #pragma unroll
            for (int nt = 0; nt < 8; ++nt) {
                uint4v bu = *(const uint4v*)(&ldsB[((s * 8 + nt) * 64 + l) * 4]);
                short8 bv = __builtin_bit_cast(short8, bu);
                acc[nt] = __builtin_amdgcn_mfma_f32_16x16x32_bf16(a0, bv, acc[nt], 0, 0, 0);
            }
        }

        // epilogue: h = relu(acc + b1); out = h . W2 + b2
        // C layout: col = lane&15 (output n), row = q*4 + reg (edge within M-tile)
        float p[4];
        #pragma unroll
        for (int r = 0; r < 4; ++r) {
            float sum = 0.f;
            #pragma unroll
            for (int nt = 0; nt < 8; ++nt)
                sum += fmaxf(acc[nt][r] + b1v[nt], 0.f) * w2v[nt];
            sum += __shfl_xor(sum, 1);
            sum += __shfl_xor(sum, 2);
            sum += __shfl_xor(sum, 4);
            sum += __shfl_xor(sum, 8);
            p[r] = sum + b2s;
        }
        if (n16 == 0) {
            int eb = tile * 128 + w * 16 + q * 4;   // 4 consecutive edges
            if (eb + 3 < E) {
                *(float4*)(out + eb) = make_float4(p[0], p[1], p[2], p[3]);
            } else {
                #pragma unroll
                for (int r = 0; r < 4; ++r)
                    if (eb + r < E) out[eb + r] = p[r];
            }
        }

        r0 = nr; c0 = nc;
    }
}

extern "C" void kernel_launch(void* const* d_in, const int* in_sizes, int n_in,
                              void* d_out, int out_size, void* d_ws, size_t ws_size,
                              hipStream_t stream) {
    const float* zc = (const float*)d_in[0];   // [N_CUST, 128] fp32
    const float* za = (const float*)d_in[1];   // [N_ART, 128] fp32
    const int*   row = (const int*)d_in[2];
    const int*   col = (const int*)d_in[3];
    const float* W1 = (const float*)d_in[4];
    const float* b1 = (const float*)d_in[5];
    const float* W2 = (const float*)d_in[6];
    const float* b2 = (const float*)d_in[7];
    float* out = (float*)d_out;

    int E = in_sizes[2];
    int ntiles = (E + 127) / 128;              // 128 edges per 512-thread block-tile
    int grid = ntiles < 512 ? ntiles : 512;    // persistent, 2 blocks/CU

    edge_mlp_f32<<<grid, 512, 0, stream>>>(zc, za, row, col, W1, b1, W2, b2, out, E, ntiles);
}